// Round 9
// baseline (5087.033 us; speedup 1.0000x reference)
//
#include <hip/hip_runtime.h>
#include <hip/hip_bf16.h>

typedef unsigned long long ull;

#define THREADS 1024
#define NWAVE 16

// ---------------- DPP helpers (rounds 5-8 validated) ----------------------
template<int CTRL, int RM>
__device__ __forceinline__ float fmax_dpp(float v) {
    int s = __builtin_amdgcn_update_dpp(__float_as_int(v), __float_as_int(v), CTRL, RM, 0xf, false);
    return fmaxf(v, __int_as_float(s));
}
template<int CTRL, int RM>
__device__ __forceinline__ float fmin_dpp(float v) {
    int s = __builtin_amdgcn_update_dpp(__float_as_int(v), __float_as_int(v), CTRL, RM, 0xf, false);
    return fminf(v, __int_as_float(s));
}
template<int CTRL, int RM>
__device__ __forceinline__ float fadd_dpp(float v) {
    int s = __builtin_amdgcn_update_dpp(0, __float_as_int(v), CTRL, RM, 0xf, false);
    return v + __int_as_float(s);
}
template<int CTRL, int RM>
__device__ __forceinline__ ull kmax_dpp(ull k) {
    unsigned hi = (unsigned)(k >> 32), lo = (unsigned)k;
    unsigned hi2 = (unsigned)__builtin_amdgcn_update_dpp((int)hi, (int)hi, CTRL, RM, 0xf, false);
    unsigned lo2 = (unsigned)__builtin_amdgcn_update_dpp((int)lo, (int)lo, CTRL, RM, 0xf, false);
    ull k2 = ((ull)hi2 << 32) | lo2;
    return (k2 > k) ? k2 : k;
}
__device__ __forceinline__ float wave_fmax(float v) {
    v = fmax_dpp<0x111,0xf>(v); v = fmax_dpp<0x112,0xf>(v);
    v = fmax_dpp<0x114,0xf>(v); v = fmax_dpp<0x118,0xf>(v);
    v = fmax_dpp<0x142,0xa>(v); v = fmax_dpp<0x143,0xc>(v);
    return v;                       // total in lane 63
}
__device__ __forceinline__ float wave_fmin(float v) {
    v = fmin_dpp<0x111,0xf>(v); v = fmin_dpp<0x112,0xf>(v);
    v = fmin_dpp<0x114,0xf>(v); v = fmin_dpp<0x118,0xf>(v);
    v = fmin_dpp<0x142,0xa>(v); v = fmin_dpp<0x143,0xc>(v);
    return v;
}
// 32-lane (half-wave) reduces: lane31 = result for lanes 0-31, lane63 for 32-63
__device__ __forceinline__ float half_fsum(float v) {
    v = fadd_dpp<0x111,0xf>(v); v = fadd_dpp<0x112,0xf>(v);
    v = fadd_dpp<0x114,0xf>(v); v = fadd_dpp<0x118,0xf>(v);
    v = fadd_dpp<0x142,0xa>(v);
    return v;
}
__device__ __forceinline__ float half_fmax(float v) {
    v = fmax_dpp<0x111,0xf>(v); v = fmax_dpp<0x112,0xf>(v);
    v = fmax_dpp<0x114,0xf>(v); v = fmax_dpp<0x118,0xf>(v);
    v = fmax_dpp<0x142,0xa>(v);
    return v;
}
__device__ __forceinline__ ull half_kmax(ull k) {
    k = kmax_dpp<0x111,0xf>(k); k = kmax_dpp<0x112,0xf>(k);
    k = kmax_dpp<0x114,0xf>(k); k = kmax_dpp<0x118,0xf>(k);
    k = kmax_dpp<0x142,0xa>(k);
    return k;
}
__device__ __forceinline__ ull wave_kmax(ull k) {
    k = half_kmax(k);
    k = kmax_dpp<0x143,0xc>(k);
    return k;
}
__device__ __forceinline__ int morton4(int x, int y, int z) {
    int r = 0;
#pragma unroll
    for (int k = 0; k < 4; ++k)
        r |= ((x >> k & 1) << (3 * k)) | ((y >> k & 1) << (3 * k + 1)) | ((z >> k & 1) << (3 * k + 2));
    return r;
}
__device__ __forceinline__ int cellof(float x, float y, float z,
                                      float bx, float by, float bz,
                                      float ivx, float ivy, float ivz) {
    int ix = (int)((x - bx) * ivx); ix = ix < 0 ? 0 : (ix > 15 ? 15 : ix);
    int iy = (int)((y - by) * ivy); iy = iy < 0 ? 0 : (iy > 15 ? 15 : iy);
    int iz = (int)((z - bz) * ivz); iz = iz < 0 ? 0 : (iz > 15 ? 15 : iz);
    return morton4(ix, iy, iz);
}

// Exact grouped lazy-prune FPS (round-8 structure, round-9 refinements):
// 32-pt groups (tighter spheres), pair-of-groups per wave-task, depth-2
// software-pipelined gx loads, u64 (distbits<<15 | 0x7fff-orig) keys that
// make tie-break implicit (max key = max dist, then min orig = np.argmax
// first-occurrence), ballot-compacted update list.
// Pruning is conservative-exact: a skipped group provably has
// d(p,c)^2 >= (d(c,q)-r)^2 >= gmax >= dist[p] for all members, so no dist
// changes; exactness never depends on the bound quality.
__global__ __launch_bounds__(THREADS)
void fps_grouped(const float* __restrict__ C, float4* __restrict__ gxyzo,
                 int n, int m, int G32, int NPAIR, int* __restrict__ idx_out) {
    const int b = blockIdx.x;
    const int t = threadIdx.x;
    const int lane = t & 63;
    const int wid  = t >> 6;
    const int GP = NPAIR * 64;
    const float* __restrict__ P = C + (size_t)b * n * 3;
    float4* __restrict__ gx = gxyzo + (size_t)b * GP;

    extern __shared__ char smem[];
    float4* s_meta = (float4*)smem;                               // G32 (+pad grp)
    ull*    s_gkey = (ull*)(smem + 16 * G32);                     // 1024
    ull*    s_part = s_gkey + 1024;                               // 2*16
    int*    s_misc = (int*)(s_part + 32);                         // 32 ints
    float*  s_red  = (float*)(s_misc + 32);                       // 96 floats
    unsigned short* s_list = (unsigned short*)(s_red + 96);       // 1024
    int distofs = ((16 * G32 + 11008) + 15) & ~15;
    float*  s_dist = (float*)(smem + distofs);                    // GP floats
    unsigned* s_hist = (unsigned*)s_dist;                         // 4096 alias (preproc)

    // ---- P1: bbox ----
    float mnx = 1e30f, mny = 1e30f, mnz = 1e30f;
    float mxx = -1e30f, mxy = -1e30f, mxz = -1e30f;
    for (int g = t; g < n; g += THREADS) {
        float x = P[3 * g], y = P[3 * g + 1], z = P[3 * g + 2];
        mnx = fminf(mnx, x); mxx = fmaxf(mxx, x);
        mny = fminf(mny, y); mxy = fmaxf(mxy, y);
        mnz = fminf(mnz, z); mxz = fmaxf(mxz, z);
    }
    mnx = wave_fmin(mnx); mny = wave_fmin(mny); mnz = wave_fmin(mnz);
    mxx = wave_fmax(mxx); mxy = wave_fmax(mxy); mxz = wave_fmax(mxz);
    if (lane == 63) {
        s_red[wid * 6 + 0] = mnx; s_red[wid * 6 + 1] = mny; s_red[wid * 6 + 2] = mnz;
        s_red[wid * 6 + 3] = mxx; s_red[wid * 6 + 4] = mxy; s_red[wid * 6 + 5] = mxz;
    }
    __syncthreads();
    if (t == 0) {
        float a0 = 1e30f, a1 = 1e30f, a2 = 1e30f, b0 = -1e30f, b1 = -1e30f, b2 = -1e30f;
        for (int w = 0; w < NWAVE; ++w) {
            a0 = fminf(a0, s_red[w * 6 + 0]); a1 = fminf(a1, s_red[w * 6 + 1]);
            a2 = fminf(a2, s_red[w * 6 + 2]); b0 = fmaxf(b0, s_red[w * 6 + 3]);
            b1 = fmaxf(b1, s_red[w * 6 + 4]); b2 = fmaxf(b2, s_red[w * 6 + 5]);
        }
        s_red[0] = a0; s_red[1] = a1; s_red[2] = a2;
        s_red[3] = 15.9999f / (b0 - a0 + 1e-20f);
        s_red[4] = 15.9999f / (b1 - a1 + 1e-20f);
        s_red[5] = 15.9999f / (b2 - a2 + 1e-20f);
    }
    __syncthreads();
    const float bx = s_red[0], by = s_red[1], bz = s_red[2];
    const float ivx = s_red[3], ivy = s_red[4], ivz = s_red[5];

    // ---- P2: histogram ----
    for (int i = t; i < 4096; i += THREADS) s_hist[i] = 0;
    __syncthreads();
    for (int g = t; g < n; g += THREADS) {
        float x = P[3 * g], y = P[3 * g + 1], z = P[3 * g + 2];
        atomicAdd(&s_hist[cellof(x, y, z, bx, by, bz, ivx, ivy, ivz)], 1u);
    }
    __syncthreads();

    // ---- P3: exclusive scan over 4096 cells ----
    {
        unsigned c0 = s_hist[4 * t], c1 = s_hist[4 * t + 1];
        unsigned c2 = s_hist[4 * t + 2], c3 = s_hist[4 * t + 3];
        unsigned sum4 = c0 + c1 + c2 + c3;
        unsigned incl = sum4;
        for (int off = 1; off < 64; off <<= 1) {
            unsigned u = (unsigned)__shfl_up((int)incl, off);
            if (lane >= off) incl += u;
        }
        if (lane == 63) s_misc[8 + wid] = (int)incl;
        __syncthreads();
        unsigned woff = 0;
        for (int w = 0; w < wid; ++w) woff += (unsigned)s_misc[8 + w];
        unsigned base = woff + incl - sum4;
        s_hist[4 * t]     = base;
        s_hist[4 * t + 1] = base + c0;
        s_hist[4 * t + 2] = base + c0 + c1;
        s_hist[4 * t + 3] = base + c0 + c1 + c2;
    }
    __syncthreads();

    // ---- P4: scatter (sorted coords + orig idx in .w) ----
    for (int g = t; g < n; g += THREADS) {
        float x = P[3 * g], y = P[3 * g + 1], z = P[3 * g + 2];
        unsigned pos = atomicAdd(&s_hist[cellof(x, y, z, bx, by, bz, ivx, ivy, ivz)], 1u);
        gx[pos] = make_float4(x, y, z, (float)g);
    }
    __syncthreads();

    // ---- P5: per-32-pt-group metadata + init (one group per wave, lanes 0-31) ----
    const ull BIGKEY = ((ull)__float_as_uint(1e10f) << 15) | 0x7fffULL;
    const int GTOT = 2 * NPAIR;            // includes possible all-pad group
    for (int g = wid; g < GTOT; g += NWAVE) {
        int cnt = n - g * 32; if (cnt > 32) cnt = 32; if (cnt < 0) cnt = 0;
        bool memb = (lane < cnt);          // lanes 32-63: false
        float x = 0.f, y = 0.f, z = 0.f;
        if (memb) {
            float4 w = gx[g * 32 + lane];
            x = w.x; y = w.y; z = w.z;
        }
        float cntf = (float)(cnt > 0 ? cnt : 1);
        float qx = __shfl(half_fsum(x), 31) / cntf;
        float qy = __shfl(half_fsum(y), 31) / cntf;
        float qz = __shfl(half_fsum(z), 31) / cntf;
        float ex = x - qx, ey = y - qy, ez = z - qz;
        float e2 = memb ? (ex * ex + ey * ey + ez * ez) : 0.0f;
        float r = sqrtf(__shfl(half_fmax(e2), 31)) * 1.0001f + 1e-6f;
        if (lane == 0) {
            s_meta[g] = make_float4(qx, qy, qz, r);
            s_gkey[g] = cnt ? BIGKEY : 0;   // force iter-1 update of real groups
        }
        if (lane < 32) {
            if (!memb) gx[g * 32 + lane] = make_float4(0.f, 0.f, 0.f, 0.f);
            s_dist[g * 32 + lane] = memb ? 1e10f : -1.0f;
        }
    }
    for (int i = t; i < 1024; i += THREADS)
        if (i >= GTOT) s_gkey[i] = 0;
    if (t == 0) { s_misc[0] = 0; idx_out[(size_t)b * m] = 0; }
    __threadfence();
    __syncthreads();

    // ---- main loop ----
    float lx = P[0], ly = P[1], lz = P[2];
    const size_t iobase = (size_t)b * m;
    for (int it = 1; it < m; ++it) {
        const int par = (it & 1) * 16;

        // Phase A: prune test per pair (both 32-pt groups), ballot compaction
        bool upd = false;
        if (t < NPAIR) {
#pragma unroll
            for (int h = 0; h < 2; ++h) {
                int g = 2 * t + h;
                if (g < G32) {
                    float4 mt = s_meta[g];
                    float gmax = __uint_as_float((unsigned)(s_gkey[g] >> 15));
                    float ax = lx - mt.x, ay = ly - mt.y, az = lz - mt.z;
                    float lb = sqrtf(ax * ax + ay * ay + az * az) - mt.w;
                    if (!(lb > 0.0f && lb * lb * 0.9999f - 1e-6f >= gmax)) upd = true;
                }
            }
        }
        {
            ull mask = __ballot(upd);
            if (mask) {
                int cnt = __popcll(mask);
                int base = 0;
                if (lane == 0) base = atomicAdd(&s_misc[0], cnt);
                base = __shfl(base, 0);
                if (upd) {
                    int pw = (int)__popcll(mask & ((1ULL << lane) - 1ULL));
                    s_list[base + pw] = (unsigned short)t;
                }
            }
        }
        __syncthreads();                       // (1)
        const int U = s_misc[0];

        // Phase C: update flagged pairs; depth-2 pipelined gx loads
        {
            int li = wid;
            int q0 = 0, q1 = 0;
            float4 w0 = make_float4(0,0,0,0), w1 = w0;
            if (li < U)      { q0 = s_list[li];      w0 = gx[q0 * 64 + lane]; }
            if (li + 16 < U) { q1 = s_list[li + 16]; w1 = gx[q1 * 64 + lane]; }
            while (li < U) {
                int lf = li + 32; int qf = 0; float4 wf = make_float4(0,0,0,0);
                if (lf < U) { qf = s_list[lf]; wf = gx[qf * 64 + lane]; }
                int gp = q0 * 64 + lane;
                float dc = s_dist[gp];
                float dx = __fsub_rn(w0.x, lx);
                float dy = __fsub_rn(w0.y, ly);
                float dz = __fsub_rn(w0.z, lz);
                float d  = __fadd_rn(__fadd_rn(__fmul_rn(dx, dx), __fmul_rn(dy, dy)),
                                     __fmul_rn(dz, dz));
                float nd = fminf(dc, d);
                s_dist[gp] = nd;
                int orig = (int)w0.w;
                ull key = ((ull)__float_as_uint(nd) << 15)
                        | (ull)(unsigned)(0x7fff - orig);
                if (nd < 0.0f) key = 0;        // pads always lose
                key = half_kmax(key);          // lane31: grp 2q0; lane63: grp 2q0+1
                if ((lane & 31) == 31) s_gkey[q0 * 2 + (lane >> 5)] = key;
                li += 16; q0 = q1; w0 = w1; q1 = qf; w1 = wf;
            }
        }
        __syncthreads();                       // (2)

        // Phase D: block argmax over group keys
        ull kk = wave_kmax(s_gkey[t]);
        if (lane == 63) s_part[par + wid] = kk;
        if (t == 0) s_misc[0] = 0;
        __syncthreads();                       // (3)
        ull k2 = s_part[par + (t & 15)];
        k2 = kmax_dpp<0x111,0xf>(k2);
        k2 = kmax_dpp<0x112,0xf>(k2);
        k2 = kmax_dpp<0x114,0xf>(k2);
        k2 = kmax_dpp<0x118,0xf>(k2);          // lane 15 = total
        int lo15 = __builtin_amdgcn_readlane((int)(unsigned)k2, 15);
        int orig = 0x7fff - (lo15 & 0x7fff);
        if (t == 0) idx_out[iobase + it] = orig;
        const float* __restrict__ wp = P + 3 * (size_t)orig;   // uniform scalar load
        lx = wp[0]; ly = wp[1]; lz = wp[2];
    }
}

// Fallback for n > 32767 (not hit for this shape): exact brute force.
__global__ __launch_bounds__(1024)
void fps_brute(const float* __restrict__ C, float* __restrict__ gdist,
               int n, int m, int* __restrict__ idx_out) {
    const int b = blockIdx.x, t = threadIdx.x;
    const int lane = t & 63, wid = t >> 6;
    const float* __restrict__ P = C + (size_t)b * n * 3;
    float* __restrict__ dist = gdist + (size_t)b * n;
    __shared__ ull sp[2][16];
    for (int g = t; g < n; g += 1024) dist[g] = 1e10f;
    if (t == 0) idx_out[(size_t)b * m] = 0;
    float lx = P[0], ly = P[1], lz = P[2];
    __syncthreads();
    for (int it = 1; it < m; ++it) {
        int par = it & 1;
        ull k = 0;
        for (int g = t; g < n; g += 1024) {
            float dx = __fsub_rn(P[3 * g], lx);
            float dy = __fsub_rn(P[3 * g + 1], ly);
            float dz = __fsub_rn(P[3 * g + 2], lz);
            float d = __fadd_rn(__fadd_rn(__fmul_rn(dx, dx), __fmul_rn(dy, dy)),
                                __fmul_rn(dz, dz));
            float nd = fminf(dist[g], d);
            dist[g] = nd;
            ull kk = ((ull)__float_as_uint(nd) << 32) | (unsigned)(~g);
            if (kk > k) k = kk;
        }
        for (int off = 1; off < 64; off <<= 1) {
            ull ok = __shfl_xor(k, off);
            if (ok > k) k = ok;
        }
        if (lane == 0) sp[par][wid] = k;
        __syncthreads();
        ull kmaxv = sp[par][0];
        for (int w = 1; w < 16; ++w) { ull v = sp[par][w]; if (v > kmaxv) kmaxv = v; }
        int sbi = (int)~(unsigned)kmaxv;
        if (t == 0) idx_out[(size_t)b * m + it] = sbi;
        const float* wp = P + 3 * (size_t)(unsigned)sbi;
        lx = wp[0]; ly = wp[1]; lz = wp[2];
    }
}

__global__ void gather_kernel(const float* __restrict__ C,
                              const float* __restrict__ F,
                              const int* __restrict__ idx,
                              float* __restrict__ outC,
                              float* __restrict__ outF,
                              int n_pts, int m, int c) {
    int pair = blockIdx.x;            // b*m + s
    int b = pair / m;
    int src = idx[pair];
    size_t srcbase = (size_t)b * n_pts + src;
    const float* sF = F + srcbase * (size_t)c;
    float* dF = outF + (size_t)pair * c;
    for (int i = threadIdx.x; i < c; i += blockDim.x) dF[i] = sF[i];
    if (threadIdx.x < 3)
        outC[(size_t)pair * 3 + threadIdx.x] = C[srcbase * 3 + threadIdx.x];
}

extern "C" void kernel_launch(void* const* d_in, const int* in_sizes, int n_in,
                              void* d_out, int out_size, void* d_ws, size_t ws_size,
                              hipStream_t stream) {
    const float* C = (const float*)d_in[0];
    const float* F = (const float*)d_in[1];

    int n_total = in_sizes[0] / 3;
    int c       = in_sizes[1] / n_total;
    int bm      = out_size / (3 + c);

    int batch = 8;
    if (bm % 2000 == 0) {
        int bb = bm / 2000;
        if (bb > 0 && n_total % bb == 0 && n_total / bb >= 2000) batch = bb;
    }
    int n_pts = n_total / batch;
    int m     = (n_pts < 2000) ? n_pts : 2000;

    int* idxbuf = (int*)d_ws;
    float* outC = (float*)d_out;
    float* outF = outC + (size_t)batch * m * 3;

    int G32   = (n_pts + 31) >> 5;
    int NPAIR = (G32 + 1) >> 1;
    int GP    = NPAIR << 6;
    size_t idxbytes = (((size_t)batch * m * 4) + 255) & ~(size_t)255;
    size_t scrbytes = (size_t)batch * GP * 16;
    void* scratch;
    if (ws_size >= idxbytes + scrbytes)
        scratch = (char*)d_ws + idxbytes;
    else
        scratch = (char*)d_out + ((((size_t)out_size * 4) - scrbytes) & ~(size_t)15);

    if (n_pts <= 32767) {
        int distbytes = GP * 4; if (distbytes < 16384) distbytes = 16384;
        int distofs = ((16 * G32 + 11008) + 15) & ~15;
        size_t smem = (size_t)distofs + distbytes;
        hipFuncSetAttribute((const void*)fps_grouped,
                            hipFuncAttributeMaxDynamicSharedMemorySize, (int)smem);
        fps_grouped<<<batch, THREADS, smem, stream>>>(C, (float4*)scratch,
                                                      n_pts, m, G32, NPAIR, idxbuf);
    } else {
        fps_brute<<<batch, 1024, 0, stream>>>(C, (float*)scratch, n_pts, m, idxbuf);
    }

    gather_kernel<<<batch * m, 128, 0, stream>>>(C, F, idxbuf, outC, outF,
                                                 n_pts, m, c);
}

// Round 10
// 3990.849 us; speedup vs baseline: 1.2747x; 1.2747x over previous
//
#include <hip/hip_runtime.h>
#include <hip/hip_bf16.h>

typedef unsigned long long ull;

#define THREADS 1024
#define NWAVE 16

// ---------------- DPP helpers (rounds 5-9 validated) ----------------------
template<int CTRL, int RM>
__device__ __forceinline__ float fmax_dpp(float v) {
    int s = __builtin_amdgcn_update_dpp(__float_as_int(v), __float_as_int(v), CTRL, RM, 0xf, false);
    return fmaxf(v, __int_as_float(s));
}
template<int CTRL, int RM>
__device__ __forceinline__ float fmin_dpp(float v) {
    int s = __builtin_amdgcn_update_dpp(__float_as_int(v), __float_as_int(v), CTRL, RM, 0xf, false);
    return fminf(v, __int_as_float(s));
}
template<int CTRL, int RM>
__device__ __forceinline__ float fadd_dpp(float v) {
    int s = __builtin_amdgcn_update_dpp(0, __float_as_int(v), CTRL, RM, 0xf, false);
    return v + __int_as_float(s);
}
template<int CTRL, int RM>
__device__ __forceinline__ ull kmax_dpp(ull k) {
    unsigned hi = (unsigned)(k >> 32), lo = (unsigned)k;
    unsigned hi2 = (unsigned)__builtin_amdgcn_update_dpp((int)hi, (int)hi, CTRL, RM, 0xf, false);
    unsigned lo2 = (unsigned)__builtin_amdgcn_update_dpp((int)lo, (int)lo, CTRL, RM, 0xf, false);
    ull k2 = ((ull)hi2 << 32) | lo2;
    return (k2 > k) ? k2 : k;
}
__device__ __forceinline__ float wave_fmax(float v) {
    v = fmax_dpp<0x111,0xf>(v); v = fmax_dpp<0x112,0xf>(v);
    v = fmax_dpp<0x114,0xf>(v); v = fmax_dpp<0x118,0xf>(v);
    v = fmax_dpp<0x142,0xa>(v); v = fmax_dpp<0x143,0xc>(v);
    return v;                       // total in lane 63
}
__device__ __forceinline__ float wave_fmin(float v) {
    v = fmin_dpp<0x111,0xf>(v); v = fmin_dpp<0x112,0xf>(v);
    v = fmin_dpp<0x114,0xf>(v); v = fmin_dpp<0x118,0xf>(v);
    v = fmin_dpp<0x142,0xa>(v); v = fmin_dpp<0x143,0xc>(v);
    return v;
}
// 32-lane (half-wave) reduces: lane31 = lanes 0-31 total, lane63 = 32-63
__device__ __forceinline__ float half_fsum(float v) {
    v = fadd_dpp<0x111,0xf>(v); v = fadd_dpp<0x112,0xf>(v);
    v = fadd_dpp<0x114,0xf>(v); v = fadd_dpp<0x118,0xf>(v);
    v = fadd_dpp<0x142,0xa>(v);
    return v;
}
__device__ __forceinline__ float half_fmax(float v) {
    v = fmax_dpp<0x111,0xf>(v); v = fmax_dpp<0x112,0xf>(v);
    v = fmax_dpp<0x114,0xf>(v); v = fmax_dpp<0x118,0xf>(v);
    v = fmax_dpp<0x142,0xa>(v);
    return v;
}
__device__ __forceinline__ ull half_kmax(ull k) {
    k = kmax_dpp<0x111,0xf>(k); k = kmax_dpp<0x112,0xf>(k);
    k = kmax_dpp<0x114,0xf>(k); k = kmax_dpp<0x118,0xf>(k);
    k = kmax_dpp<0x142,0xa>(k);
    return k;
}
__device__ __forceinline__ ull wave_kmax(ull k) {
    k = half_kmax(k);
    k = kmax_dpp<0x143,0xc>(k);
    return k;
}
__device__ __forceinline__ int morton4(int x, int y, int z) {
    int r = 0;
#pragma unroll
    for (int k = 0; k < 4; ++k)
        r |= ((x >> k & 1) << (3 * k)) | ((y >> k & 1) << (3 * k + 1)) | ((z >> k & 1) << (3 * k + 2));
    return r;
}
__device__ __forceinline__ int cellof(float x, float y, float z,
                                      float bx, float by, float bz,
                                      float ivx, float ivy, float ivz) {
    int ix = (int)((x - bx) * ivx); ix = ix < 0 ? 0 : (ix > 15 ? 15 : ix);
    int iy = (int)((y - by) * ivy); iy = iy < 0 ? 0 : (iy > 15 ? 15 : iy);
    int iz = (int)((z - bz) * ivz); iz = iz < 0 ? 0 : (iz > 15 ? 15 : iz);
    return morton4(ix, iy, iz);
}

// LDS fixed-region byte offsets (dist/hist region follows at FIXED_BYTES)
#define OFS_GKEY 0          // 1024 * ull
#define OFS_MQX  8192       // 1024 * f32
#define OFS_MQY  12288
#define OFS_MQZ  16384
#define OFS_MQR  20480
#define OFS_LIST 24576      // 1024 * u16
#define OFS_PART 26624      // 32 * ull
#define OFS_MISC 26880      // 32 * int
#define OFS_RED  27008      // 96 * f32
#define FIXED_BYTES 27392

// Exact grouped lazy-prune FPS, 32-pt groups, group-granular task list.
// A skipped group provably satisfies min_p d(p,c)^2 >= (d(c,q)-r)^2 >= gmax
// >= dist_p, so no dist changes; exactness never depends on bound quality.
// Keys: (distbits<<15) | (0x7fff-orig) -- max key = max dist, ties to the
// SMALLEST original index (np.argmax first-occurrence). fp min over the
// applied-center subset equals the reference's full min (order-free).
__global__ __launch_bounds__(THREADS)
void fps_grouped(const float* __restrict__ C, float4* __restrict__ gxyzo,
                 int n, int m, int G32, int* __restrict__ idx_out) {
    const int b = blockIdx.x;
    const int t = threadIdx.x;
    const int lane = t & 63;
    const int wid  = t >> 6;
    const int half = lane >> 5;
    const int sub  = lane & 31;
    const int GP = G32 * 32;
    const float* __restrict__ P = C + (size_t)b * n * 3;
    float4* __restrict__ gx = gxyzo + (size_t)b * GP;

    extern __shared__ char smem[];
    ull*   s_gkey = (ull*)(smem + OFS_GKEY);
    float* s_mqx  = (float*)(smem + OFS_MQX);
    float* s_mqy  = (float*)(smem + OFS_MQY);
    float* s_mqz  = (float*)(smem + OFS_MQZ);
    float* s_mqr  = (float*)(smem + OFS_MQR);
    unsigned short* s_list = (unsigned short*)(smem + OFS_LIST);
    ull*   s_part = (ull*)(smem + OFS_PART);
    int*   s_misc = (int*)(smem + OFS_MISC);
    float* s_red  = (float*)(smem + OFS_RED);
    float* s_dist = (float*)(smem + FIXED_BYTES);
    unsigned* s_hist = (unsigned*)s_dist;        // alias, preproc only

    // ---- P1: bbox ----
    float mnx = 1e30f, mny = 1e30f, mnz = 1e30f;
    float mxx = -1e30f, mxy = -1e30f, mxz = -1e30f;
    for (int g = t; g < n; g += THREADS) {
        float x = P[3 * g], y = P[3 * g + 1], z = P[3 * g + 2];
        mnx = fminf(mnx, x); mxx = fmaxf(mxx, x);
        mny = fminf(mny, y); mxy = fmaxf(mxy, y);
        mnz = fminf(mnz, z); mxz = fmaxf(mxz, z);
    }
    mnx = wave_fmin(mnx); mny = wave_fmin(mny); mnz = wave_fmin(mnz);
    mxx = wave_fmax(mxx); mxy = wave_fmax(mxy); mxz = wave_fmax(mxz);
    if (lane == 63) {
        s_red[wid * 6 + 0] = mnx; s_red[wid * 6 + 1] = mny; s_red[wid * 6 + 2] = mnz;
        s_red[wid * 6 + 3] = mxx; s_red[wid * 6 + 4] = mxy; s_red[wid * 6 + 5] = mxz;
    }
    __syncthreads();
    if (t == 0) {
        float a0 = 1e30f, a1 = 1e30f, a2 = 1e30f, b0 = -1e30f, b1 = -1e30f, b2 = -1e30f;
        for (int w = 0; w < NWAVE; ++w) {
            a0 = fminf(a0, s_red[w * 6 + 0]); a1 = fminf(a1, s_red[w * 6 + 1]);
            a2 = fminf(a2, s_red[w * 6 + 2]); b0 = fmaxf(b0, s_red[w * 6 + 3]);
            b1 = fmaxf(b1, s_red[w * 6 + 4]); b2 = fmaxf(b2, s_red[w * 6 + 5]);
        }
        s_red[0] = a0; s_red[1] = a1; s_red[2] = a2;
        s_red[3] = 15.9999f / (b0 - a0 + 1e-20f);
        s_red[4] = 15.9999f / (b1 - a1 + 1e-20f);
        s_red[5] = 15.9999f / (b2 - a2 + 1e-20f);
    }
    __syncthreads();
    const float bx = s_red[0], by = s_red[1], bz = s_red[2];
    const float ivx = s_red[3], ivy = s_red[4], ivz = s_red[5];

    // ---- P2: histogram ----
    for (int i = t; i < 4096; i += THREADS) s_hist[i] = 0;
    __syncthreads();
    for (int g = t; g < n; g += THREADS) {
        float x = P[3 * g], y = P[3 * g + 1], z = P[3 * g + 2];
        atomicAdd(&s_hist[cellof(x, y, z, bx, by, bz, ivx, ivy, ivz)], 1u);
    }
    __syncthreads();

    // ---- P3: exclusive scan over 4096 cells ----
    {
        unsigned c0 = s_hist[4 * t], c1 = s_hist[4 * t + 1];
        unsigned c2 = s_hist[4 * t + 2], c3 = s_hist[4 * t + 3];
        unsigned sum4 = c0 + c1 + c2 + c3;
        unsigned incl = sum4;
        for (int off = 1; off < 64; off <<= 1) {
            unsigned u = (unsigned)__shfl_up((int)incl, off);
            if (lane >= off) incl += u;
        }
        if (lane == 63) s_misc[8 + wid] = (int)incl;
        __syncthreads();
        unsigned woff = 0;
        for (int w = 0; w < wid; ++w) woff += (unsigned)s_misc[8 + w];
        unsigned base = woff + incl - sum4;
        s_hist[4 * t]     = base;
        s_hist[4 * t + 1] = base + c0;
        s_hist[4 * t + 2] = base + c0 + c1;
        s_hist[4 * t + 3] = base + c0 + c1 + c2;
    }
    __syncthreads();

    // ---- P4: scatter (sorted coords + orig idx in .w) ----
    for (int g = t; g < n; g += THREADS) {
        float x = P[3 * g], y = P[3 * g + 1], z = P[3 * g + 2];
        unsigned pos = atomicAdd(&s_hist[cellof(x, y, z, bx, by, bz, ivx, ivy, ivz)], 1u);
        gx[pos] = make_float4(x, y, z, (float)g);
    }
    __syncthreads();

    // ---- P5: per-32-pt-group metadata + init (one group per wave) ----
    const ull BIGKEY = ((ull)__float_as_uint(1e10f) << 15) | 0x7fffULL;
    for (int g = wid; g < G32; g += NWAVE) {
        int cnt = n - g * 32; if (cnt > 32) cnt = 32;
        bool memb = (lane < 32) && (sub < cnt);
        float x = 0.f, y = 0.f, z = 0.f;
        if (memb) {
            float4 w = gx[g * 32 + sub];
            x = w.x; y = w.y; z = w.z;
        }
        float cf = (float)cnt;
        float qx = __shfl(half_fsum(x), 31) / cf;
        float qy = __shfl(half_fsum(y), 31) / cf;
        float qz = __shfl(half_fsum(z), 31) / cf;
        float ex = x - qx, ey = y - qy, ez = z - qz;
        float e2 = memb ? (ex * ex + ey * ey + ez * ez) : 0.0f;
        float r = sqrtf(__shfl(half_fmax(e2), 31)) * 1.0001f + 1e-6f;
        if (lane == 0) {
            s_mqx[g] = qx; s_mqy[g] = qy; s_mqz[g] = qz; s_mqr[g] = r;
            s_gkey[g] = BIGKEY;             // force iter-1 update
        }
        if (lane < 32) {
            if (!memb) gx[g * 32 + sub] = make_float4(0.f, 0.f, 0.f, 0.f);
            s_dist[g * 32 + sub] = memb ? 1e10f : -1.0f;
        }
    }
    for (int i = t; i < 1024; i += THREADS)
        if (i >= G32) s_gkey[i] = 0;
    if (t == 0) { s_misc[0] = 0; idx_out[(size_t)b * m] = 0; }
    __syncthreads();

    // ---- main loop ----
    float lx = P[0], ly = P[1], lz = P[2];
    const size_t iobase = (size_t)b * m;
    for (int it = 1; it < m; ++it) {
        const int par = (it & 1) * 16;

        // Phase A: prune test per 32-pt group (SoA meta: conflict-free),
        // ballot-compacted update list (one atomic per wave).
        bool upd = false;
        if (t < G32) {
            float gmax = __uint_as_float((unsigned)(s_gkey[t] >> 15));
            float ax = lx - s_mqx[t], ay = ly - s_mqy[t], az = lz - s_mqz[t];
            float dc2 = ax * ax + ay * ay + az * az;
            float lb = sqrtf(dc2) - s_mqr[t];
            upd = !(lb > 0.0f && lb * lb * 0.9999f - 1e-6f >= gmax);
        }
        {
            ull mask = __ballot(upd);
            if (mask) {
                int cnt = __popcll(mask);
                int base = 0;
                if (lane == 0) base = atomicAdd(&s_misc[0], cnt);
                base = __shfl(base, 0);
                if (upd) {
                    int pw = (int)__popcll(mask & ((1ULL << lane) - 1ULL));
                    s_list[base + pw] = (unsigned short)t;
                }
            }
        }
        __syncthreads();                       // (1)
        const int U = s_misc[0];

        // Phase C: each wave-task = 2 arbitrary list entries (lanes 0-31 ->
        // entry 2j, lanes 32-63 -> 2j+1); batch-2 wave-tasks per pass so two
        // independent vmem loads are in flight.
        {
            const int nt = (U + 1) >> 1;
            for (int j0 = wid; j0 < nt; j0 += 2 * NWAVE) {
                const int j1 = j0 + NWAVE;
                int e0 = 2 * j0 + half;
                int e1 = 2 * j1 + half;
                int g0 = (e0 < U) ? (int)s_list[e0] : -1;
                int g1 = (j1 < nt && e1 < U) ? (int)s_list[e1] : -1;
                int o0 = g0 * 32 + sub, o1 = g1 * 32 + sub;
                float4 w0 = make_float4(0.f, 0.f, 0.f, 0.f);
                float4 w1 = make_float4(0.f, 0.f, 0.f, 0.f);
                if (g0 >= 0) w0 = gx[o0];
                if (g1 >= 0) w1 = gx[o1];
                float d0 = (g0 >= 0) ? s_dist[o0] : -1.0f;
                float d1 = (g1 >= 0) ? s_dist[o1] : -1.0f;
                // task 0
                {
                    float dx = __fsub_rn(w0.x, lx);
                    float dy = __fsub_rn(w0.y, ly);
                    float dz = __fsub_rn(w0.z, lz);
                    float ds = __fadd_rn(__fadd_rn(__fmul_rn(dx, dx), __fmul_rn(dy, dy)),
                                         __fmul_rn(dz, dz));
                    float nd = fminf(d0, ds);
                    if (g0 >= 0) s_dist[o0] = nd;
                    ull k = ((ull)__float_as_uint(nd) << 15)
                          | (ull)(unsigned)(0x7fff - (int)w0.w);
                    if (nd < 0.0f) k = 0;      // pad lanes always lose
                    k = half_kmax(k);          // lane31: g of half0, lane63: half1
                    if (g0 >= 0 && sub == 31) s_gkey[g0] = k;
                }
                // task 1
                if (g1 >= 0) {
                    float dx = __fsub_rn(w1.x, lx);
                    float dy = __fsub_rn(w1.y, ly);
                    float dz = __fsub_rn(w1.z, lz);
                    float ds = __fadd_rn(__fadd_rn(__fmul_rn(dx, dx), __fmul_rn(dy, dy)),
                                         __fmul_rn(dz, dz));
                    float nd = fminf(d1, ds);
                    s_dist[o1] = nd;
                    ull k = ((ull)__float_as_uint(nd) << 15)
                          | (ull)(unsigned)(0x7fff - (int)w1.w);
                    if (nd < 0.0f) k = 0;
                    k = half_kmax(k);
                    if (sub == 31) s_gkey[g1] = k;
                }
            }
        }
        __syncthreads();                       // (2)

        // Phase D: block argmax over 1024 group keys
        ull kk = wave_kmax(s_gkey[t]);
        if (lane == 63) s_part[par + wid] = kk;
        if (t == 0) s_misc[0] = 0;
        __syncthreads();                       // (3)
        ull k2 = s_part[par + (t & 15)];
        k2 = kmax_dpp<0x111,0xf>(k2);
        k2 = kmax_dpp<0x112,0xf>(k2);
        k2 = kmax_dpp<0x114,0xf>(k2);
        k2 = kmax_dpp<0x118,0xf>(k2);          // lane 15 = total
        int lo15 = __builtin_amdgcn_readlane((int)(unsigned)k2, 15);
        int orig = 0x7fff - (lo15 & 0x7fff);
        if (t == 0) idx_out[iobase + it] = orig;
        const float* __restrict__ wp = P + 3 * (size_t)orig;   // uniform scalar load
        lx = wp[0]; ly = wp[1]; lz = wp[2];
    }
}

// Fallback for n > 32767 (not hit for this shape): exact brute force.
__global__ __launch_bounds__(1024)
void fps_brute(const float* __restrict__ C, float* __restrict__ gdist,
               int n, int m, int* __restrict__ idx_out) {
    const int b = blockIdx.x, t = threadIdx.x;
    const int lane = t & 63, wid = t >> 6;
    const float* __restrict__ P = C + (size_t)b * n * 3;
    float* __restrict__ dist = gdist + (size_t)b * n;
    __shared__ ull sp[2][16];
    for (int g = t; g < n; g += 1024) dist[g] = 1e10f;
    if (t == 0) idx_out[(size_t)b * m] = 0;
    float lx = P[0], ly = P[1], lz = P[2];
    __syncthreads();
    for (int it = 1; it < m; ++it) {
        int par = it & 1;
        ull k = 0;
        for (int g = t; g < n; g += 1024) {
            float dx = __fsub_rn(P[3 * g], lx);
            float dy = __fsub_rn(P[3 * g + 1], ly);
            float dz = __fsub_rn(P[3 * g + 2], lz);
            float d = __fadd_rn(__fadd_rn(__fmul_rn(dx, dx), __fmul_rn(dy, dy)),
                                __fmul_rn(dz, dz));
            float nd = fminf(dist[g], d);
            dist[g] = nd;
            ull kk = ((ull)__float_as_uint(nd) << 32) | (unsigned)(~g);
            if (kk > k) k = kk;
        }
        for (int off = 1; off < 64; off <<= 1) {
            ull ok = __shfl_xor(k, off);
            if (ok > k) k = ok;
        }
        if (lane == 0) sp[par][wid] = k;
        __syncthreads();
        ull kmaxv = sp[par][0];
        for (int w = 1; w < 16; ++w) { ull v = sp[par][w]; if (v > kmaxv) kmaxv = v; }
        int sbi = (int)~(unsigned)kmaxv;
        if (t == 0) idx_out[(size_t)b * m + it] = sbi;
        const float* wp = P + 3 * (size_t)(unsigned)sbi;
        lx = wp[0]; ly = wp[1]; lz = wp[2];
    }
}

__global__ void gather_kernel(const float* __restrict__ C,
                              const float* __restrict__ F,
                              const int* __restrict__ idx,
                              float* __restrict__ outC,
                              float* __restrict__ outF,
                              int n_pts, int m, int c) {
    int pair = blockIdx.x;            // b*m + s
    int b = pair / m;
    int src = idx[pair];
    size_t srcbase = (size_t)b * n_pts + src;
    const float* sF = F + srcbase * (size_t)c;
    float* dF = outF + (size_t)pair * c;
    for (int i = threadIdx.x; i < c; i += blockDim.x) dF[i] = sF[i];
    if (threadIdx.x < 3)
        outC[(size_t)pair * 3 + threadIdx.x] = C[srcbase * 3 + threadIdx.x];
}

extern "C" void kernel_launch(void* const* d_in, const int* in_sizes, int n_in,
                              void* d_out, int out_size, void* d_ws, size_t ws_size,
                              hipStream_t stream) {
    const float* C = (const float*)d_in[0];
    const float* F = (const float*)d_in[1];

    int n_total = in_sizes[0] / 3;
    int c       = in_sizes[1] / n_total;
    int bm      = out_size / (3 + c);

    int batch = 8;
    if (bm % 2000 == 0) {
        int bb = bm / 2000;
        if (bb > 0 && n_total % bb == 0 && n_total / bb >= 2000) batch = bb;
    }
    int n_pts = n_total / batch;
    int m     = (n_pts < 2000) ? n_pts : 2000;

    int* idxbuf = (int*)d_ws;
    float* outC = (float*)d_out;
    float* outF = outC + (size_t)batch * m * 3;

    int G32 = (n_pts + 31) >> 5;
    int GP  = G32 << 5;
    size_t idxbytes = (((size_t)batch * m * 4) + 255) & ~(size_t)255;
    size_t scrbytes = (size_t)batch * GP * 16;
    void* scratch;
    if (ws_size >= idxbytes + scrbytes)
        scratch = (char*)d_ws + idxbytes;
    else
        scratch = (char*)d_out + ((((size_t)out_size * 4) - scrbytes) & ~(size_t)15);

    if (n_pts <= 32767) {
        int distbytes = GP * 4; if (distbytes < 16384) distbytes = 16384;
        size_t smem = (size_t)FIXED_BYTES + distbytes;
        hipFuncSetAttribute((const void*)fps_grouped,
                            hipFuncAttributeMaxDynamicSharedMemorySize, (int)smem);
        fps_grouped<<<batch, THREADS, smem, stream>>>(C, (float4*)scratch,
                                                      n_pts, m, G32, idxbuf);
    } else {
        fps_brute<<<batch, 1024, 0, stream>>>(C, (float*)scratch, n_pts, m, idxbuf);
    }

    gather_kernel<<<batch * m, 128, 0, stream>>>(C, F, idxbuf, outC, outF,
                                                 n_pts, m, c);
}

// Round 11
// 3093.800 us; speedup vs baseline: 1.6443x; 1.2900x over previous
//
#include <hip/hip_runtime.h>
#include <hip/hip_bf16.h>

typedef unsigned long long ull;

#define THREADS 1024
#define NWAVE 16

// ---------------- DPP helpers (rounds 5-10 validated) ---------------------
template<int CTRL, int RM>
__device__ __forceinline__ float fmax_dpp(float v) {
    int s = __builtin_amdgcn_update_dpp(__float_as_int(v), __float_as_int(v), CTRL, RM, 0xf, false);
    return fmaxf(v, __int_as_float(s));
}
template<int CTRL, int RM>
__device__ __forceinline__ float fmin_dpp(float v) {
    int s = __builtin_amdgcn_update_dpp(__float_as_int(v), __float_as_int(v), CTRL, RM, 0xf, false);
    return fminf(v, __int_as_float(s));
}
template<int CTRL, int RM>
__device__ __forceinline__ int imin_dpp(int v) {
    int s = __builtin_amdgcn_update_dpp(v, v, CTRL, RM, 0xf, false);
    return (s < v) ? s : v;
}
template<int CTRL, int RM>
__device__ __forceinline__ ull kmax_dpp(ull k) {
    unsigned hi = (unsigned)(k >> 32), lo = (unsigned)k;
    unsigned hi2 = (unsigned)__builtin_amdgcn_update_dpp((int)hi, (int)hi, CTRL, RM, 0xf, false);
    unsigned lo2 = (unsigned)__builtin_amdgcn_update_dpp((int)lo, (int)lo, CTRL, RM, 0xf, false);
    ull k2 = ((ull)hi2 << 32) | lo2;
    return (k2 > k) ? k2 : k;
}
__device__ __forceinline__ float wave_fmax(float v) {
    v = fmax_dpp<0x111,0xf>(v); v = fmax_dpp<0x112,0xf>(v);
    v = fmax_dpp<0x114,0xf>(v); v = fmax_dpp<0x118,0xf>(v);
    v = fmax_dpp<0x142,0xa>(v); v = fmax_dpp<0x143,0xc>(v);
    return v;                       // total in lane 63
}
__device__ __forceinline__ float wave_fmin(float v) {
    v = fmin_dpp<0x111,0xf>(v); v = fmin_dpp<0x112,0xf>(v);
    v = fmin_dpp<0x114,0xf>(v); v = fmin_dpp<0x118,0xf>(v);
    v = fmin_dpp<0x142,0xa>(v); v = fmin_dpp<0x143,0xc>(v);
    return v;
}
// 32-lane (half-wave) reduces: lane31 = lanes 0-31 total, lane63 = 32-63
__device__ __forceinline__ float half_fmax(float v) {
    v = fmax_dpp<0x111,0xf>(v); v = fmax_dpp<0x112,0xf>(v);
    v = fmax_dpp<0x114,0xf>(v); v = fmax_dpp<0x118,0xf>(v);
    v = fmax_dpp<0x142,0xa>(v);
    return v;
}
__device__ __forceinline__ float half_fmin(float v) {
    v = fmin_dpp<0x111,0xf>(v); v = fmin_dpp<0x112,0xf>(v);
    v = fmin_dpp<0x114,0xf>(v); v = fmin_dpp<0x118,0xf>(v);
    v = fmin_dpp<0x142,0xa>(v);
    return v;
}
__device__ __forceinline__ int half_imin(int v) {
    v = imin_dpp<0x111,0xf>(v); v = imin_dpp<0x112,0xf>(v);
    v = imin_dpp<0x114,0xf>(v); v = imin_dpp<0x118,0xf>(v);
    v = imin_dpp<0x142,0xa>(v);
    return v;
}
__device__ __forceinline__ ull wave_kmax(ull k) {
    k = kmax_dpp<0x111,0xf>(k); k = kmax_dpp<0x112,0xf>(k);
    k = kmax_dpp<0x114,0xf>(k); k = kmax_dpp<0x118,0xf>(k);
    k = kmax_dpp<0x142,0xa>(k); k = kmax_dpp<0x143,0xc>(k);
    return k;
}
__device__ __forceinline__ int morton4(int x, int y, int z) {
    int r = 0;
#pragma unroll
    for (int k = 0; k < 4; ++k)
        r |= ((x >> k & 1) << (3 * k)) | ((y >> k & 1) << (3 * k + 1)) | ((z >> k & 1) << (3 * k + 2));
    return r;
}
__device__ __forceinline__ int cellof(float x, float y, float z,
                                      float bx, float by, float bz,
                                      float ivx, float ivy, float ivz) {
    int ix = (int)((x - bx) * ivx); ix = ix < 0 ? 0 : (ix > 15 ? 15 : ix);
    int iy = (int)((y - by) * ivy); iy = iy < 0 ? 0 : (iy > 15 ? 15 : iy);
    int iz = (int)((z - bz) * ivz); iz = iz < 0 ? 0 : (iz > 15 ? 15 : iz);
    return morton4(ix, iy, iz);
}

// LDS fixed-region byte offsets (dist/hist region follows at FIXED_BYTES)
#define OFS_GKEY 0          // 1024 * ull
#define OFS_GMAX 8192       // 1024 * f32
#define OFS_CX   12288      // AABB mid x
#define OFS_CY   16384
#define OFS_CZ   20480
#define OFS_EX   24576      // AABB half-extent x
#define OFS_EY   28672
#define OFS_EZ   32768
#define OFS_LIST 36864      // 1024 * u16
#define OFS_PART 38912      // 32 * ull
#define OFS_MISC 39168      // 32 * int
#define OFS_RED  39296      // 96 * f32
#define FIXED_BYTES 39680

// Exact grouped lazy-prune FPS, 32-pt groups, AABB bounds.
// Skipped group invariant: computed lower bound lb2 <= min_p d(p,c)^2 (with
// conservative 0.9999/-1e-6 slack for rounding); prune iff lb2 >= gmax >=
// dist_p for all members -> no dist would change. Exactness never depends
// on bound quality, only on the conservative direction.
// Keys: (distbits<<15) | (0x7fff-orig): max key = max dist, ties to the
// SMALLEST original index (np.argmax first-occurrence).
__global__ __launch_bounds__(THREADS)
void fps_grouped(const float* __restrict__ C, float4* __restrict__ gxyzo,
                 int n, int m, int G32, int* __restrict__ idx_out) {
    const int b = blockIdx.x;
    const int t = threadIdx.x;
    const int lane = t & 63;
    const int wid  = t >> 6;
    const int half = lane >> 5;
    const int sub  = lane & 31;
    const int GP = G32 * 32;
    const float* __restrict__ P = C + (size_t)b * n * 3;
    float4* __restrict__ gx = gxyzo + (size_t)b * GP;

    extern __shared__ char smem[];
    ull*   s_gkey = (ull*)(smem + OFS_GKEY);
    float* s_gmax = (float*)(smem + OFS_GMAX);
    float* s_cx   = (float*)(smem + OFS_CX);
    float* s_cy   = (float*)(smem + OFS_CY);
    float* s_cz   = (float*)(smem + OFS_CZ);
    float* s_ex   = (float*)(smem + OFS_EX);
    float* s_ey   = (float*)(smem + OFS_EY);
    float* s_ez   = (float*)(smem + OFS_EZ);
    unsigned short* s_list = (unsigned short*)(smem + OFS_LIST);
    ull*   s_part = (ull*)(smem + OFS_PART);
    int*   s_misc = (int*)(smem + OFS_MISC);
    float* s_red  = (float*)(smem + OFS_RED);
    float* s_dist = (float*)(smem + FIXED_BYTES);
    unsigned* s_hist = (unsigned*)s_dist;        // alias, preproc only

    // ---- P1: bbox ----
    float mnx = 1e30f, mny = 1e30f, mnz = 1e30f;
    float mxx = -1e30f, mxy = -1e30f, mxz = -1e30f;
    for (int g = t; g < n; g += THREADS) {
        float x = P[3 * g], y = P[3 * g + 1], z = P[3 * g + 2];
        mnx = fminf(mnx, x); mxx = fmaxf(mxx, x);
        mny = fminf(mny, y); mxy = fmaxf(mxy, y);
        mnz = fminf(mnz, z); mxz = fmaxf(mxz, z);
    }
    mnx = wave_fmin(mnx); mny = wave_fmin(mny); mnz = wave_fmin(mnz);
    mxx = wave_fmax(mxx); mxy = wave_fmax(mxy); mxz = wave_fmax(mxz);
    if (lane == 63) {
        s_red[wid * 6 + 0] = mnx; s_red[wid * 6 + 1] = mny; s_red[wid * 6 + 2] = mnz;
        s_red[wid * 6 + 3] = mxx; s_red[wid * 6 + 4] = mxy; s_red[wid * 6 + 5] = mxz;
    }
    __syncthreads();
    if (t == 0) {
        float a0 = 1e30f, a1 = 1e30f, a2 = 1e30f, b0 = -1e30f, b1 = -1e30f, b2 = -1e30f;
        for (int w = 0; w < NWAVE; ++w) {
            a0 = fminf(a0, s_red[w * 6 + 0]); a1 = fminf(a1, s_red[w * 6 + 1]);
            a2 = fminf(a2, s_red[w * 6 + 2]); b0 = fmaxf(b0, s_red[w * 6 + 3]);
            b1 = fmaxf(b1, s_red[w * 6 + 4]); b2 = fmaxf(b2, s_red[w * 6 + 5]);
        }
        s_red[0] = a0; s_red[1] = a1; s_red[2] = a2;
        s_red[3] = 15.9999f / (b0 - a0 + 1e-20f);
        s_red[4] = 15.9999f / (b1 - a1 + 1e-20f);
        s_red[5] = 15.9999f / (b2 - a2 + 1e-20f);
    }
    __syncthreads();
    const float bx = s_red[0], by = s_red[1], bz = s_red[2];
    const float ivx = s_red[3], ivy = s_red[4], ivz = s_red[5];

    // ---- P2: histogram ----
    for (int i = t; i < 4096; i += THREADS) s_hist[i] = 0;
    __syncthreads();
    for (int g = t; g < n; g += THREADS) {
        float x = P[3 * g], y = P[3 * g + 1], z = P[3 * g + 2];
        atomicAdd(&s_hist[cellof(x, y, z, bx, by, bz, ivx, ivy, ivz)], 1u);
    }
    __syncthreads();

    // ---- P3: exclusive scan over 4096 cells ----
    {
        unsigned c0 = s_hist[4 * t], c1 = s_hist[4 * t + 1];
        unsigned c2 = s_hist[4 * t + 2], c3 = s_hist[4 * t + 3];
        unsigned sum4 = c0 + c1 + c2 + c3;
        unsigned incl = sum4;
        for (int off = 1; off < 64; off <<= 1) {
            unsigned u = (unsigned)__shfl_up((int)incl, off);
            if (lane >= off) incl += u;
        }
        if (lane == 63) s_misc[8 + wid] = (int)incl;
        __syncthreads();
        unsigned woff = 0;
        for (int w = 0; w < wid; ++w) woff += (unsigned)s_misc[8 + w];
        unsigned base = woff + incl - sum4;
        s_hist[4 * t]     = base;
        s_hist[4 * t + 1] = base + c0;
        s_hist[4 * t + 2] = base + c0 + c1;
        s_hist[4 * t + 3] = base + c0 + c1 + c2;
    }
    __syncthreads();

    // ---- P4: scatter (sorted coords + orig idx in .w) ----
    for (int g = t; g < n; g += THREADS) {
        float x = P[3 * g], y = P[3 * g + 1], z = P[3 * g + 2];
        unsigned pos = atomicAdd(&s_hist[cellof(x, y, z, bx, by, bz, ivx, ivy, ivz)], 1u);
        gx[pos] = make_float4(x, y, z, (float)g);
    }
    __syncthreads();

    // ---- P5: per-32-pt-group AABB metadata + init (one group per wave) ----
    const ull BIGKEY = ((ull)__float_as_uint(1e10f) << 15) | 0x7fffULL;
    for (int g = wid; g < G32; g += NWAVE) {
        int cnt = n - g * 32; if (cnt > 32) cnt = 32;
        bool memb = (lane < 32) && (sub < cnt);
        float4 w = make_float4(0.f, 0.f, 0.f, 0.f);
        if (memb) w = gx[g * 32 + sub];
        float xn = memb ? w.x : 1e30f, xx = memb ? w.x : -1e30f;
        float yn = memb ? w.y : 1e30f, yx = memb ? w.y : -1e30f;
        float zn = memb ? w.z : 1e30f, zx = memb ? w.z : -1e30f;
        xn = __shfl(half_fmin(xn), 31); xx = __shfl(half_fmax(xx), 31);
        yn = __shfl(half_fmin(yn), 31); yx = __shfl(half_fmax(yx), 31);
        zn = __shfl(half_fmin(zn), 31); zx = __shfl(half_fmax(zx), 31);
        if (lane == 0) {
            s_cx[g] = (xn + xx) * 0.5f; s_ex[g] = (xx - xn) * 0.5f + 1e-7f;
            s_cy[g] = (yn + yx) * 0.5f; s_ey[g] = (yx - yn) * 0.5f + 1e-7f;
            s_cz[g] = (zn + zx) * 0.5f; s_ez[g] = (zx - zn) * 0.5f + 1e-7f;
            s_gmax[g] = 1e10f;          // force iter-1 update
            s_gkey[g] = BIGKEY;
        }
        if (lane < 32) {
            if (!memb) gx[g * 32 + sub] = make_float4(0.f, 0.f, 0.f, 0.f);
            s_dist[g * 32 + sub] = memb ? 1e10f : -1.0f;
        }
    }
    for (int i = t; i < 1024; i += THREADS)
        if (i >= G32) s_gkey[i] = 0;
    if (t == 0) { s_misc[0] = 0; idx_out[(size_t)b * m] = 0; }
    __syncthreads();

    // ---- main loop ----
    float lx = P[0], ly = P[1], lz = P[2];
    const size_t iobase = (size_t)b * m;
    const int DW = (G32 + 63) >> 6;        // waves with real keys in Phase D
    for (int it = 1; it < m; ++it) {
        const int par = (it & 1) * 16;

        // Phase A: AABB prune test (no sqrt), ballot-compacted list
        bool upd = false;
        if (t < G32) {
            float gmax = s_gmax[t];
            float ax = fmaxf(fabsf(lx - s_cx[t]) - s_ex[t], 0.0f);
            float ay = fmaxf(fabsf(ly - s_cy[t]) - s_ey[t], 0.0f);
            float az = fmaxf(fabsf(lz - s_cz[t]) - s_ez[t], 0.0f);
            float lb2 = ax * ax + ay * ay + az * az;
            upd = !(lb2 * 0.9999f - 1e-6f >= gmax);
        }
        {
            ull mask = __ballot(upd);
            if (mask) {
                int cnt = __popcll(mask);
                int base = 0;
                if (lane == 0) base = atomicAdd(&s_misc[0], cnt);
                base = __shfl(base, 0);
                if (upd) {
                    int pw = (int)__popcll(mask & ((1ULL << lane) - 1ULL));
                    s_list[base + pw] = (unsigned short)t;
                }
            }
        }
        __syncthreads();                       // (1)
        const int U = s_misc[0];

        // Phase C: update flagged groups; 2 groups per wave (one per half).
        // f32 half-max reduce + ballot/ffs/shfl argmax extraction; rare
        // exact-tie path does a u32 min-reduce over matched lanes.
        {
            const int nt = (U + 1) >> 1;
            for (int j0 = wid; j0 < nt; j0 += NWAVE) {
                int e = 2 * j0 + half;
                int g = (e < U) ? (int)s_list[e] : -1;
                int o = g * 32 + sub;
                float4 w = make_float4(0.f, 0.f, 0.f, 0.f);
                float dc = -1.0f;
                if (g >= 0) { w = gx[o]; dc = s_dist[o]; }
                float dx = __fsub_rn(w.x, lx);
                float dy = __fsub_rn(w.y, ly);
                float dz = __fsub_rn(w.z, lz);
                float d  = __fadd_rn(__fadd_rn(__fmul_rn(dx, dx), __fmul_rn(dy, dy)),
                                     __fmul_rn(dz, dz));
                float nd = fminf(dc, d);
                if (g >= 0) s_dist[o] = nd;
                // per-half max of nd
                float gmr = nd;
                gmr = fmax_dpp<0x111,0xf>(gmr);
                gmr = fmax_dpp<0x112,0xf>(gmr);
                gmr = fmax_dpp<0x114,0xf>(gmr);
                gmr = fmax_dpp<0x118,0xf>(gmr);
                gmr = fmax_dpp<0x142,0xa>(gmr);
                float gm = __shfl(gmr, lane | 31);         // bcast half max
                ull mask = __ballot(nd == gm);
                unsigned hm = half ? (unsigned)(mask >> 32) : (unsigned)mask;
                int fl = __ffs((int)hm) - 1;               // first matching lane
                int ao = __shfl((int)w.w, (half << 5) + fl);
                bool tie = (hm & (hm - 1u)) != 0u;
                if (__any(tie)) {                           // rare exact ties
                    int morig = (nd == gm) ? (int)w.w : 0x7FFFFFFF;
                    morig = half_imin(morig);
                    int tmin = __shfl(morig, lane | 31);
                    if (tie) ao = tmin;
                }
                if (g >= 0 && sub == 31) {
                    s_gkey[g] = ((ull)__float_as_uint(gm) << 15)
                              | (ull)(unsigned)(0x7fff - ao);
                    s_gmax[g] = gm;
                }
            }
        }
        __syncthreads();                       // (2)

        // Phase D: block argmax over group keys (only DW waves have keys)
        ull kk = 0;
        if (wid < DW) kk = wave_kmax(s_gkey[t]);
        if (lane == 63) s_part[par + wid] = kk;
        if (t == 0) s_misc[0] = 0;
        __syncthreads();                       // (3)
        ull k2 = s_part[par + (t & 15)];
        k2 = kmax_dpp<0x111,0xf>(k2);
        k2 = kmax_dpp<0x112,0xf>(k2);
        k2 = kmax_dpp<0x114,0xf>(k2);
        k2 = kmax_dpp<0x118,0xf>(k2);          // lane 15 = total
        int lo15 = __builtin_amdgcn_readlane((int)(unsigned)k2, 15);
        int orig = 0x7fff - (lo15 & 0x7fff);
        if (t == 0) idx_out[iobase + it] = orig;
        const float* __restrict__ wp = P + 3 * (size_t)orig;   // uniform scalar load
        lx = wp[0]; ly = wp[1]; lz = wp[2];
    }
}

// Fallback for n > 32767 (not hit for this shape): exact brute force.
__global__ __launch_bounds__(1024)
void fps_brute(const float* __restrict__ C, float* __restrict__ gdist,
               int n, int m, int* __restrict__ idx_out) {
    const int b = blockIdx.x, t = threadIdx.x;
    const int lane = t & 63, wid = t >> 6;
    const float* __restrict__ P = C + (size_t)b * n * 3;
    float* __restrict__ dist = gdist + (size_t)b * n;
    __shared__ ull sp[2][16];
    for (int g = t; g < n; g += 1024) dist[g] = 1e10f;
    if (t == 0) idx_out[(size_t)b * m] = 0;
    float lx = P[0], ly = P[1], lz = P[2];
    __syncthreads();
    for (int it = 1; it < m; ++it) {
        int par = it & 1;
        ull k = 0;
        for (int g = t; g < n; g += 1024) {
            float dx = __fsub_rn(P[3 * g], lx);
            float dy = __fsub_rn(P[3 * g + 1], ly);
            float dz = __fsub_rn(P[3 * g + 2], lz);
            float d = __fadd_rn(__fadd_rn(__fmul_rn(dx, dx), __fmul_rn(dy, dy)),
                                __fmul_rn(dz, dz));
            float nd = fminf(dist[g], d);
            dist[g] = nd;
            ull kk = ((ull)__float_as_uint(nd) << 32) | (unsigned)(~g);
            if (kk > k) k = kk;
        }
        for (int off = 1; off < 64; off <<= 1) {
            ull ok = __shfl_xor(k, off);
            if (ok > k) k = ok;
        }
        if (lane == 0) sp[par][wid] = k;
        __syncthreads();
        ull kmaxv = sp[par][0];
        for (int w = 1; w < 16; ++w) { ull v = sp[par][w]; if (v > kmaxv) kmaxv = v; }
        int sbi = (int)~(unsigned)kmaxv;
        if (t == 0) idx_out[(size_t)b * m + it] = sbi;
        const float* wp = P + 3 * (size_t)(unsigned)sbi;
        lx = wp[0]; ly = wp[1]; lz = wp[2];
    }
}

__global__ void gather_kernel(const float* __restrict__ C,
                              const float* __restrict__ F,
                              const int* __restrict__ idx,
                              float* __restrict__ outC,
                              float* __restrict__ outF,
                              int n_pts, int m, int c) {
    int pair = blockIdx.x;            // b*m + s
    int b = pair / m;
    int src = idx[pair];
    size_t srcbase = (size_t)b * n_pts + src;
    const float* sF = F + srcbase * (size_t)c;
    float* dF = outF + (size_t)pair * c;
    for (int i = threadIdx.x; i < c; i += blockDim.x) dF[i] = sF[i];
    if (threadIdx.x < 3)
        outC[(size_t)pair * 3 + threadIdx.x] = C[srcbase * 3 + threadIdx.x];
}

extern "C" void kernel_launch(void* const* d_in, const int* in_sizes, int n_in,
                              void* d_out, int out_size, void* d_ws, size_t ws_size,
                              hipStream_t stream) {
    const float* C = (const float*)d_in[0];
    const float* F = (const float*)d_in[1];

    int n_total = in_sizes[0] / 3;
    int c       = in_sizes[1] / n_total;
    int bm      = out_size / (3 + c);

    int batch = 8;
    if (bm % 2000 == 0) {
        int bb = bm / 2000;
        if (bb > 0 && n_total % bb == 0 && n_total / bb >= 2000) batch = bb;
    }
    int n_pts = n_total / batch;
    int m     = (n_pts < 2000) ? n_pts : 2000;

    int* idxbuf = (int*)d_ws;
    float* outC = (float*)d_out;
    float* outF = outC + (size_t)batch * m * 3;

    int G32 = (n_pts + 31) >> 5;
    int GP  = G32 << 5;
    size_t idxbytes = (((size_t)batch * m * 4) + 255) & ~(size_t)255;
    size_t scrbytes = (size_t)batch * GP * 16;
    void* scratch;
    if (ws_size >= idxbytes + scrbytes)
        scratch = (char*)d_ws + idxbytes;
    else
        scratch = (char*)d_out + ((((size_t)out_size * 4) - scrbytes) & ~(size_t)15);

    if (n_pts <= 32767) {
        int distbytes = GP * 4; if (distbytes < 16384) distbytes = 16384;
        size_t smem = (size_t)FIXED_BYTES + distbytes;
        hipFuncSetAttribute((const void*)fps_grouped,
                            hipFuncAttributeMaxDynamicSharedMemorySize, (int)smem);
        fps_grouped<<<batch, THREADS, smem, stream>>>(C, (float4*)scratch,
                                                      n_pts, m, G32, idxbuf);
    } else {
        fps_brute<<<batch, 1024, 0, stream>>>(C, (float*)scratch, n_pts, m, idxbuf);
    }

    gather_kernel<<<batch * m, 128, 0, stream>>>(C, F, idxbuf, outC, outF,
                                                 n_pts, m, c);
}